// Round 1
// baseline (250.837 us; speedup 1.0000x reference)
//
#include <hip/hip_runtime.h>

namespace {
constexpr int kB = 4, kC = 32, kH = 512, kW = 512, kN = 64;
constexpr int kHout = 16, kMaxW = 192;
constexpr long long kResultElems = (long long)kB * kN * kC * kHout * kMaxW;
}

// One block per (b, n, i): 192 threads, thread j = output column.
// Discrete decisions (width, floor taps, clips) use explicit round-to-nearest
// scalar ops in the reference's order so tap selection is bit-exact vs XLA/np.
extern "C" __global__ __launch_bounds__(kMaxW) void roi_rotate(
    const float* __restrict__ image,
    const float* __restrict__ boxes,
    float* __restrict__ result,
    float* __restrict__ mask)
{
    const int blk = blockIdx.x;
    const int i  = blk & (kHout - 1);   // output row 0..15
    const int bn = blk >> 4;            // b*N + n, 0..255
    const int b  = bn >> 6;

    const float* bx = boxes + bn * 5;
    const float left = bx[0];
    const float top  = bx[1];
    const float bw   = __fsub_rn(bx[2], bx[0]);
    const float bh   = __fsub_rn(bx[3], bx[1]);
    const int width  = (int)(__fmul_rn(__fdiv_rn(bw, bh), (float)kHout));
    const float each_w = __fdiv_rn(bw, (float)(width - 1));
    const float each_h = __fdiv_rn(bh, (float)(kHout - 1));

    const int j = threadIdx.x;          // 0..191
    // x = j*each_w + left ; y = i*each_h + top  (separate rounds, no FMA)
    const float x = __fadd_rn(__fmul_rn((float)j, each_w), left);
    const float y = __fadd_rn(__fmul_rn((float)i, each_h), top);

    const int xf = (int)floorf(x);
    const int yf = (int)floorf(y);
    const int x0 = min(max(xf,     0), kW - 1);
    const int x1 = min(max(xf + 1, 0), kW - 1);
    const int y0 = min(max(yf,     0), kH - 1);
    const int y1 = min(max(yf + 1, 0), kH - 1);

    const float wx1 = (float)x1 - x;    // (x1f - x)  (can be negative at clip)
    const float wx0 = x - (float)x0;    // (x - x0f)
    const float wy1 = (float)y1 - y;
    const float wy0 = y - (float)y0;
    const float wa = wx1 * wy1;
    const float wb = wx1 * wy0;
    const float wc = wx0 * wy1;
    const float wd = wx0 * wy0;

    const bool valid = (j < width);

    float* op = result + (size_t)bn * (kC * kHout * kMaxW) + (size_t)i * kMaxW + j;

    if (valid) {
        const float* ch = image + (size_t)b * ((size_t)kC * kH * kW);
        const size_t oa = (size_t)y0 * kW + x0;
        const size_t ob = (size_t)y1 * kW + x0;
        const size_t oc = (size_t)y0 * kW + x1;
        const size_t od = (size_t)y1 * kW + x1;
        #pragma unroll 8
        for (int c = 0; c < kC; ++c) {
            const float va = ch[oa];
            const float vb = ch[ob];
            const float vc = ch[oc];
            const float vd = ch[od];
            op[0] = va * wa + vb * wb + vc * wc + vd * wd;  // ref sum order
            ch += (size_t)kH * kW;
            op += kHout * kMaxW;
        }
    } else {
        #pragma unroll 8
        for (int c = 0; c < kC; ++c) {
            op[0] = 0.0f;               // d_out is poisoned; must write zeros
            op += kHout * kMaxW;
        }
    }

    if (i == 0) {
        mask[bn * kMaxW + j] = valid ? 1.0f : 0.0f;
    }
}

extern "C" void kernel_launch(void* const* d_in, const int* in_sizes, int n_in,
                              void* d_out, int out_size, void* d_ws, size_t ws_size,
                              hipStream_t stream) {
    const float* image = (const float*)d_in[0];
    const float* boxes = (const float*)d_in[1];
    float* result = (float*)d_out;
    float* mask   = result + kResultElems;   // outputs concatenated flat

    dim3 grid(kB * kN * kHout);   // 4096 blocks: (b,n,i)
    dim3 block(kMaxW);            // 192 threads = 3 waves, thread = column j
    hipLaunchKernelGGL(roi_rotate, grid, block, 0, stream,
                       image, boxes, result, mask);
}

// Round 2
// 224.360 us; speedup vs baseline: 1.1180x; 1.1180x over previous
//
#include <hip/hip_runtime.h>

namespace {
constexpr int kB = 4, kC = 32, kH = 512, kW = 512, kN = 64;
constexpr int kHout = 16, kMaxW = 192;
constexpr long long kResultElems = (long long)kB * kN * kC * kHout * kMaxW;
}

// One block per (b, n, i): 192 threads, thread j = output column.
// The 4 bilinear taps for every j in a block come from just 2 image rows
// (y0,y1) over an x-span of <= 512 px. Stage those rows into LDS with
// aligned float4 coalesced loads (2 channels per barrier pass), then sample
// from LDS -- turns the 4B gather (3-18 cachelines per wave-load) into
// full-cacheline vector loads.
// Discrete decisions (width, floor taps, clips) use explicit round-to-nearest
// scalar ops in the reference's order so tap selection is bit-exact vs numpy.
extern "C" __global__ __launch_bounds__(kMaxW) void roi_rotate(
    const float* __restrict__ image,
    const float* __restrict__ boxes,
    float* __restrict__ result,
    float* __restrict__ mask)
{
    __shared__ float ls[2][2][kW];   // [channel_pair][row(y0/y1)][x] : 8 KiB

    const int blk = blockIdx.x;
    const int i  = blk & (kHout - 1);   // output row 0..15
    const int bn = blk >> 4;            // b*N + n
    const int b  = bn >> 6;

    const float* bx = boxes + bn * 5;
    const float left = bx[0];
    const float top  = bx[1];
    const float bw   = __fsub_rn(bx[2], bx[0]);
    const float bh   = __fsub_rn(bx[3], bx[1]);
    const int width  = (int)(__fmul_rn(__fdiv_rn(bw, bh), (float)kHout));
    const float each_w = __fdiv_rn(bw, (float)(width - 1));
    const float each_h = __fdiv_rn(bh, (float)(kHout - 1));

    const int j = threadIdx.x;          // 0..191
    const float x = __fadd_rn(__fmul_rn((float)j, each_w), left);
    const float y = __fadd_rn(__fmul_rn((float)i, each_h), top);

    const int xf = (int)floorf(x);
    const int yf = (int)floorf(y);
    const int x0 = min(max(xf,     0), kW - 1);
    const int x1 = min(max(xf + 1, 0), kW - 1);
    const int y0 = min(max(yf,     0), kH - 1);
    const int y1 = min(max(yf + 1, 0), kH - 1);

    const float wx1 = (float)x1 - x;
    const float wx0 = x - (float)x0;
    const float wy1 = (float)y1 - y;
    const float wy0 = y - (float)y0;
    const float wa = wx1 * wy1;
    const float wb = wx1 * wy0;
    const float wc = wx0 * wy1;
    const float wd = wx0 * wy0;

    const bool valid = (j < width);     // width in [16,184] for this input dist

    // Staging extent (uniform across block). For valid j: x in [left, left+bw],
    // so clip(floor(x)) >= clip(floor(left)) >= xlo and x1 <= xhi.
    const int xlo = (min(max((int)floorf(left), 0), kW - 1)) & ~3;  // 16B aligned
    const int xhi = min((int)floorf(__fadd_rn(left, bw)) + 1, kW - 1);
    const int S    = xhi - xlo + 1;      // <= 512
    const int nvec = (S + 3) >> 2;       // float4 loads per row, <= 128 (< 192)
    // float4 tail may over-read <= 3 floats past xhi within the same row
    // (or into the next row start); y1 <= 497 here (top<=432, bh<=64), so the
    // over-read never leaves the image allocation.

    const bool do_stage = (j < nvec);
    const size_t row_off0 = (size_t)y0 * kW + xlo;
    const size_t row_off1 = (size_t)y1 * kW + xlo;
    const int lx0 = x0 - xlo;
    const int lx1 = x1 - xlo;

    float* op = result + (size_t)bn * (kC * kHout * kMaxW) + (size_t)i * kMaxW + j;
    const float* chbase = image + (size_t)b * ((size_t)kC * kH * kW);
    constexpr size_t kChStride = (size_t)kH * kW;
    constexpr int kOpStride = kHout * kMaxW;

    for (int c = 0; c < kC; c += 2) {
        const float* p0 = chbase + (size_t)c * kChStride;
        const float* p1 = p0 + kChStride;
        if (do_stage) {
            const int o = 4 * j;
            const float4 v00 = *(const float4*)(p0 + row_off0 + o);
            const float4 v01 = *(const float4*)(p0 + row_off1 + o);
            const float4 v10 = *(const float4*)(p1 + row_off0 + o);
            const float4 v11 = *(const float4*)(p1 + row_off1 + o);
            *(float4*)&ls[0][0][o] = v00;
            *(float4*)&ls[0][1][o] = v01;
            *(float4*)&ls[1][0][o] = v10;
            *(float4*)&ls[1][1][o] = v11;
        }
        __syncthreads();
        float out0 = 0.0f, out1 = 0.0f;
        if (valid) {
            out0 = ls[0][0][lx0] * wa + ls[0][1][lx0] * wb
                 + ls[0][0][lx1] * wc + ls[0][1][lx1] * wd;
            out1 = ls[1][0][lx0] * wa + ls[1][1][lx0] * wb
                 + ls[1][0][lx1] * wc + ls[1][1][lx1] * wd;
        }
        op[0]         = out0;           // d_out is poisoned: invalid j writes 0
        op[kOpStride] = out1;
        op += 2 * kOpStride;
        __syncthreads();
    }

    if (i == 0) {
        mask[bn * kMaxW + j] = valid ? 1.0f : 0.0f;
    }
}

extern "C" void kernel_launch(void* const* d_in, const int* in_sizes, int n_in,
                              void* d_out, int out_size, void* d_ws, size_t ws_size,
                              hipStream_t stream) {
    const float* image = (const float*)d_in[0];
    const float* boxes = (const float*)d_in[1];
    float* result = (float*)d_out;
    float* mask   = result + kResultElems;   // outputs concatenated flat

    dim3 grid(kB * kN * kHout);   // 4096 blocks: (b,n,i)
    dim3 block(kMaxW);            // 192 threads = 3 waves
    hipLaunchKernelGGL(roi_rotate, grid, block, 0, stream,
                       image, boxes, result, mask);
}